// Round 1
// baseline (1153.672 us; speedup 1.0000x reference)
//
#include <hip/hip_runtime.h>
#include <hip/hip_bf16.h>
#include <math.h>

#define S_TOT 1536
#define S0    1024
#define HID   1024
#define HEADS 16
#define HD    64
#define INTER 4096
#define NLAYERS 4
#define KCONV 768
#define EPSV  1e-5f
#define SCALEV 0.125f
#define QKVS  3072   // fused qkv row stride (fp32 gemm out)
#define QKS   2048   // fused rope'd q|k bf16 row stride

typedef __attribute__((ext_vector_type(8))) __bf16 bf16x8;
typedef __attribute__((ext_vector_type(8))) unsigned short u16x8;
typedef __attribute__((ext_vector_type(4))) float f32x4;
typedef __attribute__((address_space(1))) void gvoid;
typedef __attribute__((address_space(3))) void lvoid;

__device__ __forceinline__ ushort f2bf(float f) {
    union { float f; unsigned u; } v; v.f = f;
    unsigned u = v.u;
    return (ushort)((u + 0x7FFFu + ((u >> 16) & 1u)) >> 16);
}
__device__ __forceinline__ float bf2f(ushort b) {
    union { unsigned u; float f; } v; v.u = ((unsigned)b) << 16;
    return v.f;
}

// ---------------- weight converts ----------------
__global__ __launch_bounds__(256) void cvt_kernel(
    const float* __restrict__ src, ushort* __restrict__ dst, int n4)
{
    int i = blockIdx.x * 256 + threadIdx.x;
    if (i < n4) {
        float4 v = ((const float4*)src)[i];
        ushort4 o;
        o.x = f2bf(v.x); o.y = f2bf(v.y); o.z = f2bf(v.z); o.w = f2bf(v.w);
        ((ushort4*)dst)[i] = o;
    }
}

// fused per-layer weight convert: dst = [qkv(3M) | o(1M) | gate(4M) | up(4M) | down(4M)]
__global__ __launch_bounds__(256) void cvt_layer_kernel(
    const float* __restrict__ qw, const float* __restrict__ kw,
    const float* __restrict__ vw, const float* __restrict__ ow,
    const float* __restrict__ gw, const float* __restrict__ uw,
    const float* __restrict__ dw, ushort* __restrict__ dst)
{
    int i = blockIdx.x * 256 + threadIdx.x;   // 4-elem group, 4M groups
    int e = i << 2;
    const float* src; int off;
    if      (e < (1  << 20)) { src = qw; off = e; }
    else if (e < (2  << 20)) { src = kw; off = e - (1 << 20); }
    else if (e < (3  << 20)) { src = vw; off = e - (2 << 20); }
    else if (e < (4  << 20)) { src = ow; off = e - (3 << 20); }
    else if (e < (8  << 20)) { src = gw; off = e - (4 << 20); }
    else if (e < (12 << 20)) { src = uw; off = e - (8 << 20); }
    else                     { src = dw; off = e - (12 << 20); }
    float4 v = *(const float4*)(src + off);
    ushort4 o;
    o.x = f2bf(v.x); o.y = f2bf(v.y); o.z = f2bf(v.z); o.w = f2bf(v.w);
    *(ushort4*)(dst + e) = o;
}

// ---------------- im2col (bf16 out) ----------------
__global__ __launch_bounds__(256) void im2col_kernel(
    const float* __restrict__ img0, const float* __restrict__ img1,
    ushort* __restrict__ P)
{
    int s = blockIdx.x;
    const float* img; int W, ph, pw;
    if (s < S0) { img = img0; W = 512; ph = s >> 5; pw = s & 31; }
    else { int t = s - S0; img = img1; W = 256; ph = t >> 4; pw = t & 15; }
    for (int k = threadIdx.x; k < KCONV; k += 256) {
        int c = k >> 8; int r = k & 255; int y = r >> 4; int x = r & 15;
        P[(size_t)s * KCONV + k] =
            f2bf(img[(size_t)c * 512 * W + (size_t)(ph * 16 + y) * W + (pw * 16 + x)]);
    }
}

// ---------------- MFMA bf16 GEMM: C[M][N] = A[M][K] * B[N][K]^T (+ D) ----------------
template<int BM, int BN, bool OUT_BF16>
__global__ __launch_bounds__(256) void mfma_gemm_bt(
    const ushort* __restrict__ A, const ushort* __restrict__ B,
    const float* __restrict__ D, void* __restrict__ Cout,
    int M, int N, int K)
{
    constexpr int WMT = BM / 32;
    constexpr int WNT = BN / 32;
    __shared__ ushort As[BM * 32];
    __shared__ ushort Bs[BN * 32];
    const int t = threadIdx.x;
    const int bm = blockIdx.x * BM, bn = blockIdx.y * BN;
    const int wave = t >> 6, lane = t & 63;
    const int wm = (wave & 1) * (BM / 2), wn = (wave >> 1) * (BN / 2);
    const int frow = lane & 15, fq = lane >> 4;
    f32x4 acc[WMT][WNT];
    #pragma unroll
    for (int i = 0; i < WMT; ++i)
        #pragma unroll
        for (int j = 0; j < WNT; ++j) acc[i][j] = (f32x4){0.f, 0.f, 0.f, 0.f};

    for (int k0 = 0; k0 < K; k0 += 32) {
        __syncthreads();
        #pragma unroll
        for (int i = 0; i < BM * 4; i += 256) {
            int idx = t + i;
            int r = idx >> 2, c8 = (idx & 3) << 3;
            __builtin_amdgcn_global_load_lds(
                (gvoid*)(A + (size_t)(bm + r) * K + k0 + c8),
                (lvoid*)(As + idx * 8), 16, 0, 0);
        }
        #pragma unroll
        for (int i = 0; i < BN * 4; i += 256) {
            int idx = t + i;
            int r = idx >> 2, c8 = (idx & 3) << 3;
            __builtin_amdgcn_global_load_lds(
                (gvoid*)(B + (size_t)(bn + r) * K + k0 + c8),
                (lvoid*)(Bs + idx * 8), 16, 0, 0);
        }
        __syncthreads();
        bf16x8 af[WMT], bfr[WNT];
        #pragma unroll
        for (int i = 0; i < WMT; ++i)
            af[i] = *(const bf16x8*)(As + (wm + 16 * i + frow) * 32 + fq * 8);
        #pragma unroll
        for (int j = 0; j < WNT; ++j)
            bfr[j] = *(const bf16x8*)(Bs + (wn + 16 * j + frow) * 32 + fq * 8);
        #pragma unroll
        for (int i = 0; i < WMT; ++i)
            #pragma unroll
            for (int j = 0; j < WNT; ++j)
                acc[i][j] = __builtin_amdgcn_mfma_f32_16x16x32_bf16(
                    af[i], bfr[j], acc[i][j], 0, 0, 0);
    }
    #pragma unroll
    for (int i = 0; i < WMT; ++i) {
        #pragma unroll
        for (int j = 0; j < WNT; ++j) {
            #pragma unroll
            for (int r = 0; r < 4; ++r) {
                int row = bm + wm + 16 * i + fq * 4 + r;
                int col = bn + wn + 16 * j + frow;
                float vv = acc[i][j][r];
                if (D) vv += D[(size_t)row * N + col];
                if (OUT_BF16) ((ushort*)Cout)[(size_t)row * N + col] = f2bf(vv);
                else          ((float*)Cout)[(size_t)row * N + col] = vv;
            }
        }
    }
}

// ---------------- MFMA bf16 GEMM, 128x128 tile, split-K, atomic accumulate ----------------
// Cout must be pre-loaded with the additive base (residual). Each z-block handles K/SPLITK.
// Rationale: N=1024 outputs give only 96 blocks at 128^2 -> split-K restores occupancy while
// keeping 16 MFMA/wave per barrier (vs 4 in the 64^2 template that measured MfmaUtil=8%).
template<int SPLITK>
__global__ __launch_bounds__(256) void mfma_gemm_bt_sk(
    const ushort* __restrict__ A, const ushort* __restrict__ B,
    float* __restrict__ Cout, int M, int N, int K)
{
    constexpr int BM = 128, BN = 128;
    __shared__ ushort As[BM * 32];
    __shared__ ushort Bs[BN * 32];
    const int t = threadIdx.x;
    const int bm = blockIdx.x * BM, bn = blockIdx.y * BN;
    const int kc = K / SPLITK;
    const int kbeg = blockIdx.z * kc;
    const int wave = t >> 6, lane = t & 63;
    const int wm = (wave & 1) * 64, wn = (wave >> 1) * 64;
    const int frow = lane & 15, fq = lane >> 4;
    f32x4 acc[4][4];
    #pragma unroll
    for (int i = 0; i < 4; ++i)
        #pragma unroll
        for (int j = 0; j < 4; ++j) acc[i][j] = (f32x4){0.f, 0.f, 0.f, 0.f};

    for (int k0 = kbeg; k0 < kbeg + kc; k0 += 32) {
        __syncthreads();
        #pragma unroll
        for (int i = 0; i < BM * 4; i += 256) {
            int idx = t + i;
            int r = idx >> 2, c8 = (idx & 3) << 3;
            __builtin_amdgcn_global_load_lds(
                (gvoid*)(A + (size_t)(bm + r) * K + k0 + c8),
                (lvoid*)(As + idx * 8), 16, 0, 0);
        }
        #pragma unroll
        for (int i = 0; i < BN * 4; i += 256) {
            int idx = t + i;
            int r = idx >> 2, c8 = (idx & 3) << 3;
            __builtin_amdgcn_global_load_lds(
                (gvoid*)(B + (size_t)(bn + r) * K + k0 + c8),
                (lvoid*)(Bs + idx * 8), 16, 0, 0);
        }
        __syncthreads();
        bf16x8 af[4], bfr[4];
        #pragma unroll
        for (int i = 0; i < 4; ++i)
            af[i] = *(const bf16x8*)(As + (wm + 16 * i + frow) * 32 + fq * 8);
        #pragma unroll
        for (int j = 0; j < 4; ++j)
            bfr[j] = *(const bf16x8*)(Bs + (wn + 16 * j + frow) * 32 + fq * 8);
        #pragma unroll
        for (int i = 0; i < 4; ++i)
            #pragma unroll
            for (int j = 0; j < 4; ++j)
                acc[i][j] = __builtin_amdgcn_mfma_f32_16x16x32_bf16(
                    af[i], bfr[j], acc[i][j], 0, 0, 0);
    }
    // hardware f32 fadd atomics (device scope): accumulate partials onto residual base
    #pragma unroll
    for (int i = 0; i < 4; ++i) {
        #pragma unroll
        for (int j = 0; j < 4; ++j) {
            #pragma unroll
            for (int r = 0; r < 4; ++r) {
                int row = bm + wm + 16 * i + fq * 4 + r;
                int col = bn + wn + 16 * j + frow;
                unsafeAtomicAdd(&Cout[(size_t)row * N + col], acc[i][j][r]);
            }
        }
    }
}

// ---------------- RMS norm fp32->fp32 ----------------
__global__ __launch_bounds__(256) void rms_kernel(
    const float* __restrict__ in, const float* __restrict__ w,
    float* __restrict__ out)
{
    int row = blockIdx.x;
    const float* xr = in + (size_t)row * HID;
    float ss = 0.f;
    for (int i = threadIdx.x; i < HID; i += 256) { float v = xr[i]; ss += v * v; }
    #pragma unroll
    for (int off = 32; off > 0; off >>= 1) ss += __shfl_down(ss, off, 64);
    __shared__ float red[4];
    int wid = threadIdx.x >> 6;
    if ((threadIdx.x & 63) == 0) red[wid] = ss;
    __syncthreads();
    if (threadIdx.x == 0)
        red[0] = rsqrtf((red[0] + red[1] + red[2] + red[3]) / HID + EPSV);
    __syncthreads();
    float rs = red[0];
    for (int i = threadIdx.x; i < HID; i += 256)
        out[(size_t)row * HID + i] = xr[i] * rs * w[i];
}

// ---------------- RMS norm fp32->bf16 ----------------
__global__ __launch_bounds__(256) void rms_bf_kernel(
    const float* __restrict__ in, const float* __restrict__ w,
    ushort* __restrict__ out)
{
    int row = blockIdx.x;
    const float* xr = in + (size_t)row * HID;
    float ss = 0.f;
    for (int i = threadIdx.x; i < HID; i += 256) { float v = xr[i]; ss += v * v; }
    #pragma unroll
    for (int off = 32; off > 0; off >>= 1) ss += __shfl_down(ss, off, 64);
    __shared__ float red[4];
    int wid = threadIdx.x >> 6;
    if ((threadIdx.x & 63) == 0) red[wid] = ss;
    __syncthreads();
    if (threadIdx.x == 0)
        red[0] = rsqrtf((red[0] + red[1] + red[2] + red[3]) / HID + EPSV);
    __syncthreads();
    float rs = red[0];
    for (int i = threadIdx.x; i < HID; i += 256)
        out[(size_t)row * HID + i] = f2bf(xr[i] * rs * w[i]);
}

// ---------------- RoPE tables ----------------
__global__ void rope_tab_kernel(float* __restrict__ cs, float* __restrict__ sn)
{
    int s = blockIdx.x; int j = threadIdx.x; // 32 threads
    int h, w;
    if (s < S0) { h = s >> 5; w = s & 31; }
    else { int t = s - S0; h = t >> 4; w = t & 15; }
    float f;
    if (j < 16) f = (float)h * powf(10000.f, -(4.f * j) / 64.f);
    else        f = (float)w * powf(10000.f, -(4.f * (j - 16) + 2.f) / 64.f);
    cs[s * 32 + j] = cosf(f);
    sn[s * 32 + j] = sinf(f);
}

// ---------------- RoPE q,k fp32 -> bf16 qkb[1536][2048] ----------------
__global__ __launch_bounds__(256) void rope_bf_kernel(
    const float* __restrict__ qkv, ushort* __restrict__ qkb,
    const float* __restrict__ cs, const float* __restrict__ sn)
{
    int idx = blockIdx.x * 256 + threadIdx.x;   // S_TOT*2048
    int s = idx >> 11, c = idx & 2047;
    int part = c >> 10, cc = c & 1023;
    int hh = cc >> 6, d = cc & 63, j = d & 31;
    size_t base = (size_t)s * QKVS + part * 1024 + hh * HD;
    float xa = qkv[base + j], xb = qkv[base + 32 + j];
    float cv = cs[s * 32 + j], sv = sn[s * 32 + j];
    float out = (d < 32) ? (xa * cv - xb * sv) : (xb * cv + xa * sv);
    qkb[idx] = f2bf(out);
}

// ---------------- V transpose fp32 qkv -> bf16 vT[head][d][s] ----------------
__global__ __launch_bounds__(256) void vtrans_kernel(
    const float* __restrict__ qkv, ushort* __restrict__ vT)
{
    __shared__ float T[64][65];
    int st = blockIdx.x;   // s-tile (24)
    int hh = blockIdx.y;   // head
    int s0 = st << 6;
    int t = threadIdx.x;
    #pragma unroll
    for (int i = 0; i < 16; i += 4) {
        int u = t + ((i >> 2) << 8);     // 4 iters of 256 -> 1024 float4 units
        int r = u >> 4, c4 = (u & 15) << 2;
        float4 v = *(const float4*)(qkv + (size_t)(s0 + r) * QKVS + 2048 + hh * HD + c4);
        T[r][c4 + 0] = v.x; T[r][c4 + 1] = v.y; T[r][c4 + 2] = v.z; T[r][c4 + 3] = v.w;
    }
    __syncthreads();
    int d = t >> 2, sg = (t & 3) << 4;
    ushort buf[16];
    #pragma unroll
    for (int j = 0; j < 16; ++j) buf[j] = f2bf(T[sg + j][d]);
    ushort* dst = vT + ((size_t)hh * HD + d) * S_TOT + s0 + sg;
    *(u16x8*)dst = *(u16x8*)buf;
    *(u16x8*)(dst + 8) = *(u16x8*)(buf + 8);
}

// ---------------- MFMA flash attention ----------------
// block = (q-tile of 64, head); 4 waves x 16 q-rows; k-tiles of 64 keys.
// Ks[key][d] pitch 72, Vt[d][key] pitch 72, Ps[wave][q][key] pitch 72 (all bf16).
__global__ __launch_bounds__(256) void flash_mfma_kernel(
    const ushort* __restrict__ qkb, const ushort* __restrict__ vT,
    ushort* __restrict__ o)
{
    __shared__ ushort Ks[64 * 72];
    __shared__ ushort Vt[64 * 72];
    __shared__ ushort Ps[4 * 16 * 72];
    int tile = blockIdx.x;
    int hh = blockIdx.y;
    int segStart, q0, nkt;
    if (tile < 16) { segStart = 0; q0 = tile << 6; nkt = 16; }
    else { segStart = S0; q0 = S0 + ((tile - 16) << 6); nkt = 8; }
    const int t = threadIdx.x;
    const int wave = t >> 6, lane = t & 63;
    const int c = lane & 15, fq = lane >> 4;
    const int wq = wave << 4;
    ushort* Pw = Ps + wave * 16 * 72;

    // Q fragments direct from global (A-operand layout), reused across all k-tiles
    bf16x8 qf[2];
    #pragma unroll
    for (int ks = 0; ks < 2; ++ks)
        qf[ks] = *(const bf16x8*)(qkb + (size_t)(q0 + wq + c) * QKS + hh * HD + ks * 32 + fq * 8);

    float m_i[4], l_i[4];
    f32x4 accO[4];
    #pragma unroll
    for (int r = 0; r < 4; ++r) { m_i[r] = -1e30f; l_i[r] = 0.f; }
    #pragma unroll
    for (int nt = 0; nt < 4; ++nt) accO[nt] = (f32x4){0.f, 0.f, 0.f, 0.f};

    for (int kt = 0; kt < nkt; ++kt) {
        int kbase = segStart + (kt << 6);
        __syncthreads();
        // stage K rows (bf16, row-major) and Vt rows (bf16, d-major from global vT)
        #pragma unroll
        for (int i = 0; i < 2; ++i) {
            int u = t + (i << 8);            // 512 ushort8 units
            int r = u >> 3, c8 = (u & 7) << 3;
            u16x8 kv = *(const u16x8*)(qkb + (size_t)(kbase + r) * QKS + 1024 + hh * HD + c8);
            *(u16x8*)(Ks + r * 72 + c8) = kv;
            u16x8 vv = *(const u16x8*)(vT + ((size_t)hh * HD + r) * S_TOT + kbase + c8);
            *(u16x8*)(Vt + r * 72 + c8) = vv;
        }
        __syncthreads();

        // QK^T: scores C[q=fq*4+r][key=nt*16+c]
        f32x4 acc[4];
        #pragma unroll
        for (int nt = 0; nt < 4; ++nt) acc[nt] = (f32x4){0.f, 0.f, 0.f, 0.f};
        #pragma unroll
        for (int ks = 0; ks < 2; ++ks) {
            #pragma unroll
            for (int nt = 0; nt < 4; ++nt) {
                bf16x8 bfr = *(const bf16x8*)(Ks + (nt * 16 + c) * 72 + ks * 32 + fq * 8);
                acc[nt] = __builtin_amdgcn_mfma_f32_16x16x32_bf16(qf[ks], bfr, acc[nt], 0, 0, 0);
            }
        }

        // online softmax (per q-row r), P -> LDS (bf16, A-operand layout)
        #pragma unroll
        for (int r = 0; r < 4; ++r) {
            float s0v = acc[0][r] * SCALEV, s1v = acc[1][r] * SCALEV;
            float s2v = acc[2][r] * SCALEV, s3v = acc[3][r] * SCALEV;
            float rm = fmaxf(fmaxf(s0v, s1v), fmaxf(s2v, s3v));
            #pragma unroll
            for (int msk = 1; msk < 16; msk <<= 1)
                rm = fmaxf(rm, __shfl_xor(rm, msk, 64));
            float mn = fmaxf(m_i[r], rm);
            float al = __expf(m_i[r] - mn);
            float p0 = __expf(s0v - mn), p1 = __expf(s1v - mn);
            float p2 = __expf(s2v - mn), p3 = __expf(s3v - mn);
            float rs = p0 + p1 + p2 + p3;
            #pragma unroll
            for (int msk = 1; msk < 16; msk <<= 1)
                rs += __shfl_xor(rs, msk, 64);
            l_i[r] = l_i[r] * al + rs;
            m_i[r] = mn;
            #pragma unroll
            for (int nt = 0; nt < 4; ++nt) accO[nt][r] *= al;
            int qrow = (fq << 2) + r;
            Pw[qrow * 72 + 0  + c] = f2bf(p0);
            Pw[qrow * 72 + 16 + c] = f2bf(p1);
            Pw[qrow * 72 + 32 + c] = f2bf(p2);
            Pw[qrow * 72 + 48 + c] = f2bf(p3);
        }

        // PV: O[q][d=nt*16+c] += P[q][key] * V[key][d]
        #pragma unroll
        for (int ks = 0; ks < 2; ++ks) {
            bf16x8 pa = *(const bf16x8*)(Pw + c * 72 + ks * 32 + fq * 8);
            #pragma unroll
            for (int nt = 0; nt < 4; ++nt) {
                bf16x8 bv = *(const bf16x8*)(Vt + (nt * 16 + c) * 72 + ks * 32 + fq * 8);
                accO[nt] = __builtin_amdgcn_mfma_f32_16x16x32_bf16(pa, bv, accO[nt], 0, 0, 0);
            }
        }
    }

    // epilogue
    #pragma unroll
    for (int r = 0; r < 4; ++r) {
        float inv = 1.f / l_i[r];
        int row = q0 + wq + (fq << 2) + r;
        #pragma unroll
        for (int nt = 0; nt < 4; ++nt)
            o[(size_t)row * HID + hh * HD + nt * 16 + c] = f2bf(accO[nt][r] * inv);
    }
}

// ---------------- SiLU(gate)*up from fused bf16 [S][8192] -> bf16 [S][4096] ----------------
__global__ __launch_bounds__(256) void silu_mul_bf_kernel(
    const ushort* __restrict__ gu, ushort* __restrict__ gb)
{
    int i = blockIdx.x * 256 + threadIdx.x;   // S_TOT*INTER
    int s = i >> 12, cc = i & 4095;
    float x = bf2f(gu[(size_t)s * 8192 + cc]);
    float u = bf2f(gu[(size_t)s * 8192 + 4096 + cc]);
    float sg = 1.f / (1.f + __expf(-x));
    gb[i] = f2bf(x * sg * u);
}

// ---------------- copy to out ----------------
__global__ __launch_bounds__(256) void copy_kernel(
    const float* __restrict__ src, float* __restrict__ dst, int n)
{
    int i = blockIdx.x * 256 + threadIdx.x;
    if (i < n) dst[i] = src[i];
}

extern "C" void kernel_launch(void* const* d_in, const int* in_sizes, int n_in,
                              void* d_out, int out_size, void* d_ws, size_t ws_size,
                              hipStream_t stream)
{
    const float* img0        = (const float*)d_in[0];
    const float* img1        = (const float*)d_in[1];
    const float* conv_w      = (const float*)d_in[2];
    const float* ln_pre_w    = (const float*)d_in[3];
    const float* attn_norm_w = (const float*)d_in[4];
    const float* q_w         = (const float*)d_in[5];
    const float* k_w         = (const float*)d_in[6];
    const float* v_w         = (const float*)d_in[7];
    const float* o_w         = (const float*)d_in[8];
    const float* ffn_norm_w  = (const float*)d_in[9];
    const float* gate_w      = (const float*)d_in[10];
    const float* up_w        = (const float*)d_in[11];
    const float* down_w      = (const float*)d_in[12];

    char* p = (char*)d_ws;
    float* x    = (float*)p;   p += (size_t)1572864 * 4;   // [1536][1024]
    float* qkv  = (float*)p;   p += (size_t)4718592 * 4;   // [1536][3072]
    float* cs   = (float*)p;   p += (size_t)49152 * 4;
    float* sn   = (float*)p;   p += (size_t)49152 * 4;
    ushort* qkb = (ushort*)p;  p += (size_t)3145728 * 2;   // [1536][2048] rope'd q|k bf16
    ushort* vTb = (ushort*)p;  p += (size_t)1572864 * 2;   // [16][64][1536] V^T bf16
    ushort* hnb = (ushort*)p;  p += (size_t)1572864 * 2;   // [1536][1024]
    ushort* obb = (ushort*)p;  p += (size_t)1572864 * 2;   // [1536][1024]
    ushort* gub = (ushort*)p;  p += (size_t)12582912 * 2;  // [1536][8192]
    ushort* gb  = (ushort*)p;  p += (size_t)6291456 * 2;   // [1536][4096]
    ushort* Pb  = (ushort*)p;  p += (size_t)1179648 * 2;   // [1536][768]
    ushort* cvb = (ushort*)p;  p += (size_t)786432 * 2;    // conv_w bf16
    ushort* wbuf= (ushort*)p;  p += (size_t)16777216 * 2;  // per-layer weights

    ushort* wqkv = wbuf;                 // [3072][1024]
    ushort* wo   = wbuf + 3145728;       // [1024][1024]
    ushort* wgu  = wbuf + 4194304;       // [8192][1024]
    ushort* wdn  = wbuf + 12582912;      // [1024][4096]

    dim3 blk(256);

    cvt_kernel<<<768, blk, 0, stream>>>(conv_w, cvb, 786432 / 4);
    im2col_kernel<<<S_TOT, blk, 0, stream>>>(img0, img1, Pb);
    mfma_gemm_bt<64, 64, false><<<dim3(24, 16), blk, 0, stream>>>(
        Pb, cvb, nullptr, x, S_TOT, HID, KCONV);
    rms_kernel<<<S_TOT, blk, 0, stream>>>(x, ln_pre_w, x);
    rope_tab_kernel<<<S_TOT, 32, 0, stream>>>(cs, sn);

    for (int l = 0; l < NLAYERS; ++l) {
        cvt_layer_kernel<<<16384, blk, 0, stream>>>(
            q_w + (size_t)l * 1048576, k_w + (size_t)l * 1048576,
            v_w + (size_t)l * 1048576, o_w + (size_t)l * 1048576,
            gate_w + (size_t)l * 4194304, up_w + (size_t)l * 4194304,
            down_w + (size_t)l * 4194304, wbuf);

        rms_bf_kernel<<<S_TOT, blk, 0, stream>>>(x, attn_norm_w + (size_t)l * HID, hnb);
        mfma_gemm_bt<128, 128, false><<<dim3(12, 24), blk, 0, stream>>>(
            hnb, wqkv, nullptr, qkv, S_TOT, QKVS, HID);
        rope_bf_kernel<<<(S_TOT * QKS) / 256, blk, 0, stream>>>(qkv, qkb, cs, sn);
        vtrans_kernel<<<dim3(24, HEADS), blk, 0, stream>>>(qkv, vTb);
        flash_mfma_kernel<<<dim3(24, HEADS), blk, 0, stream>>>(qkb, vTb, obb);
        // o-projection: x += obb * wo^T  (128^2 tile, split-K=4, hw fadd atomics;
        // x already holds the residual)
        mfma_gemm_bt_sk<4><<<dim3(12, 8, 4), blk, 0, stream>>>(
            obb, wo, x, S_TOT, HID, HID);
        rms_bf_kernel<<<S_TOT, blk, 0, stream>>>(x, ffn_norm_w + (size_t)l * HID, hnb);
        mfma_gemm_bt<128, 128, true><<<dim3(12, 64), blk, 0, stream>>>(
            hnb, wgu, nullptr, gub, S_TOT, 2 * INTER, HID);
        silu_mul_bf_kernel<<<(S_TOT * INTER) / 256, blk, 0, stream>>>(gub, gb);
        // down-projection: x += gb * wdn^T  (128^2 tile, split-K=8 -> 768 blocks x 16 K-steps,
        // replaces the 64^2 path that measured MfmaUtil=8% / 59.6 us)
        mfma_gemm_bt_sk<8><<<dim3(12, 8, 8), blk, 0, stream>>>(
            gb, wdn, x, S_TOT, HID, INTER);
    }
    copy_kernel<<<(S_TOT * HID) / 256, blk, 0, stream>>>(x, (float*)d_out, S_TOT * HID);
}

// Round 2
// 999.730 us; speedup vs baseline: 1.1540x; 1.1540x over previous
//
#include <hip/hip_runtime.h>
#include <hip/hip_bf16.h>
#include <math.h>

#define S_TOT 1536
#define S0    1024
#define HID   1024
#define HEADS 16
#define HD    64
#define INTER 4096
#define NLAYERS 4
#define KCONV 768
#define EPSV  1e-5f
#define SCALEV 0.125f
#define QKVS  3072   // fused qkv row stride (fp32 gemm out)
#define QKS   2048   // fused rope'd q|k bf16 row stride

typedef __attribute__((ext_vector_type(8))) __bf16 bf16x8;
typedef __attribute__((ext_vector_type(8))) unsigned short u16x8;
typedef __attribute__((ext_vector_type(4))) float f32x4;
typedef __attribute__((address_space(1))) void gvoid;
typedef __attribute__((address_space(3))) void lvoid;

__device__ __forceinline__ ushort f2bf(float f) {
    union { float f; unsigned u; } v; v.f = f;
    unsigned u = v.u;
    return (ushort)((u + 0x7FFFu + ((u >> 16) & 1u)) >> 16);
}
__device__ __forceinline__ float bf2f(ushort b) {
    union { unsigned u; float f; } v; v.u = ((unsigned)b) << 16;
    return v.f;
}

// counted vmcnt wait with compile-time immediate
template<int N> __device__ __forceinline__ void wait_vm() {
    if constexpr (N == 0)      asm volatile("s_waitcnt vmcnt(0)" ::: "memory");
    else if constexpr (N == 2) asm volatile("s_waitcnt vmcnt(2)" ::: "memory");
    else if constexpr (N == 4) asm volatile("s_waitcnt vmcnt(4)" ::: "memory");
    else if constexpr (N == 8) asm volatile("s_waitcnt vmcnt(8)" ::: "memory");
    else                       asm volatile("s_waitcnt vmcnt(0)" ::: "memory");
}

// ---------------- weight converts ----------------
__global__ __launch_bounds__(256) void cvt_kernel(
    const float* __restrict__ src, ushort* __restrict__ dst, int n4)
{
    int i = blockIdx.x * 256 + threadIdx.x;
    if (i < n4) {
        float4 v = ((const float4*)src)[i];
        ushort4 o;
        o.x = f2bf(v.x); o.y = f2bf(v.y); o.z = f2bf(v.z); o.w = f2bf(v.w);
        ((ushort4*)dst)[i] = o;
    }
}

// fused per-layer weight convert: dst = [qkv(3M) | o(1M) | gate(4M) | up(4M) | down(4M)]
__global__ __launch_bounds__(256) void cvt_layer_kernel(
    const float* __restrict__ qw, const float* __restrict__ kw,
    const float* __restrict__ vw, const float* __restrict__ ow,
    const float* __restrict__ gw, const float* __restrict__ uw,
    const float* __restrict__ dw, ushort* __restrict__ dst)
{
    int i = blockIdx.x * 256 + threadIdx.x;   // 4-elem group, 4M groups
    int e = i << 2;
    const float* src; int off;
    if      (e < (1  << 20)) { src = qw; off = e; }
    else if (e < (2  << 20)) { src = kw; off = e - (1 << 20); }
    else if (e < (3  << 20)) { src = vw; off = e - (2 << 20); }
    else if (e < (4  << 20)) { src = ow; off = e - (3 << 20); }
    else if (e < (8  << 20)) { src = gw; off = e - (4 << 20); }
    else if (e < (12 << 20)) { src = uw; off = e - (8 << 20); }
    else                     { src = dw; off = e - (12 << 20); }
    float4 v = *(const float4*)(src + off);
    ushort4 o;
    o.x = f2bf(v.x); o.y = f2bf(v.y); o.z = f2bf(v.z); o.w = f2bf(v.w);
    *(ushort4*)(dst + e) = o;
}

// ---------------- im2col (bf16 out) ----------------
__global__ __launch_bounds__(256) void im2col_kernel(
    const float* __restrict__ img0, const float* __restrict__ img1,
    ushort* __restrict__ P)
{
    int s = blockIdx.x;
    const float* img; int W, ph, pw;
    if (s < S0) { img = img0; W = 512; ph = s >> 5; pw = s & 31; }
    else { int t = s - S0; img = img1; W = 256; ph = t >> 4; pw = t & 15; }
    for (int k = threadIdx.x; k < KCONV; k += 256) {
        int c = k >> 8; int r = k & 255; int y = r >> 4; int x = r & 15;
        P[(size_t)s * KCONV + k] =
            f2bf(img[(size_t)c * 512 * W + (size_t)(ph * 16 + y) * W + (pw * 16 + x)]);
    }
}

// ============ 2-phase double-buffered MFMA bf16 GEMM core ============
// C[M][N] = A[M][K] * B[N][K]^T. Next K-tile's global_load_lds issued BEFORE the
// current tile's compute; counted vmcnt (never 0 mid-loop) so loads stay in
// flight across barriers. Two raw barriers/step, no full drain (T3 minimum-2ph).
template<int BM, int BN, bool OUT_BF16>
__global__ __launch_bounds__(256) void gemm2p(
    const ushort* __restrict__ A, const ushort* __restrict__ B,
    void* __restrict__ Cout, int M, int N, int K)
{
    constexpr int WMT = BM / 32, WNT = BN / 32;
    constexpr int NLA = (BM * 32) / (8 * 256);   // 16B loads per thread for A tile
    constexpr int NLB = (BN * 32) / (8 * 256);
    constexpr int NL  = NLA + NLB;
    __shared__ ushort As[2][BM * 32];
    __shared__ ushort Bs[2][BN * 32];
    const int t = threadIdx.x;
    const int bm = blockIdx.x * BM, bn = blockIdx.y * BN;
    const int wave = t >> 6, lane = t & 63;
    const int wm = (wave & 1) * (BM / 2), wn = (wave >> 1) * (BN / 2);
    const int frow = lane & 15, fq = lane >> 4;

    auto stage = [&](int b, int k0) {
        #pragma unroll
        for (int i = 0; i < NLA; ++i) {
            int idx = t + i * 256;
            int r = idx >> 2, c8 = (idx & 3) << 3;
            __builtin_amdgcn_global_load_lds(
                (gvoid*)(A + (size_t)(bm + r) * K + k0 + c8),
                (lvoid*)(&As[b][idx * 8]), 16, 0, 0);
        }
        #pragma unroll
        for (int i = 0; i < NLB; ++i) {
            int idx = t + i * 256;
            int r = idx >> 2, c8 = (idx & 3) << 3;
            __builtin_amdgcn_global_load_lds(
                (gvoid*)(B + (size_t)(bn + r) * K + k0 + c8),
                (lvoid*)(&Bs[b][idx * 8]), 16, 0, 0);
        }
    };

    f32x4 acc[WMT][WNT];
    #pragma unroll
    for (int i = 0; i < WMT; ++i)
        #pragma unroll
        for (int j = 0; j < WNT; ++j) acc[i][j] = (f32x4){0.f, 0.f, 0.f, 0.f};

    stage(0, 0);
    int cur = 0;
    for (int k0 = 0; k0 < K; k0 += 32) {
        const bool more = (k0 + 32) < K;
        if (more) { stage(cur ^ 1, k0 + 32); wait_vm<NL>(); }
        else      { wait_vm<0>(); }
        __builtin_amdgcn_s_barrier();            // everyone's cur-tile loads landed
        __builtin_amdgcn_sched_barrier(0);
        bf16x8 af[WMT], bfr[WNT];
        #pragma unroll
        for (int i = 0; i < WMT; ++i)
            af[i] = *(const bf16x8*)(&As[cur][(wm + 16 * i + frow) * 32 + fq * 8]);
        #pragma unroll
        for (int j = 0; j < WNT; ++j)
            bfr[j] = *(const bf16x8*)(&Bs[cur][(wn + 16 * j + frow) * 32 + fq * 8]);
        asm volatile("s_waitcnt lgkmcnt(0)" ::: "memory");
        __builtin_amdgcn_sched_barrier(0);
        __builtin_amdgcn_s_barrier();            // buffer free for next stage
        #pragma unroll
        for (int i = 0; i < WMT; ++i)
            #pragma unroll
            for (int j = 0; j < WNT; ++j)
                acc[i][j] = __builtin_amdgcn_mfma_f32_16x16x32_bf16(
                    af[i], bfr[j], acc[i][j], 0, 0, 0);
        cur ^= 1;
    }
    #pragma unroll
    for (int i = 0; i < WMT; ++i) {
        #pragma unroll
        for (int j = 0; j < WNT; ++j) {
            #pragma unroll
            for (int r = 0; r < 4; ++r) {
                int row = bm + wm + 16 * i + fq * 4 + r;
                int col = bn + wn + 16 * j + frow;
                float vv = acc[i][j][r];
                if (OUT_BF16) ((ushort*)Cout)[(size_t)row * N + col] = f2bf(vv);
                else          ((float*)Cout)[(size_t)row * N + col] = vv;
            }
        }
    }
}

// ============ 2-phase split-K GEMM: writes f32 partial slabs (no atomics) ============
// P[z][M*N]; a separate reduce kernel sums slabs onto the residual.
template<int SPLITK>
__global__ __launch_bounds__(256) void gemm2p_sk(
    const ushort* __restrict__ A, const ushort* __restrict__ B,
    float* __restrict__ P, int M, int N, int K)
{
    constexpr int BM = 128, BN = 128;
    constexpr int NL = 4;                       // 2 loads A + 2 loads B per thread
    __shared__ ushort As[2][BM * 32];
    __shared__ ushort Bs[2][BN * 32];
    const int t = threadIdx.x;
    const int bm = blockIdx.x * BM, bn = blockIdx.y * BN;
    const int kc = K / SPLITK;
    const int kb = blockIdx.z * kc, ke = kb + kc;
    const int wave = t >> 6, lane = t & 63;
    const int wm = (wave & 1) * 64, wn = (wave >> 1) * 64;
    const int frow = lane & 15, fq = lane >> 4;

    auto stage = [&](int b, int k0) {
        #pragma unroll
        for (int i = 0; i < 2; ++i) {
            int idx = t + i * 256;
            int r = idx >> 2, c8 = (idx & 3) << 3;
            __builtin_amdgcn_global_load_lds(
                (gvoid*)(A + (size_t)(bm + r) * K + k0 + c8),
                (lvoid*)(&As[b][idx * 8]), 16, 0, 0);
        }
        #pragma unroll
        for (int i = 0; i < 2; ++i) {
            int idx = t + i * 256;
            int r = idx >> 2, c8 = (idx & 3) << 3;
            __builtin_amdgcn_global_load_lds(
                (gvoid*)(B + (size_t)(bn + r) * K + k0 + c8),
                (lvoid*)(&Bs[b][idx * 8]), 16, 0, 0);
        }
    };

    f32x4 acc[4][4];
    #pragma unroll
    for (int i = 0; i < 4; ++i)
        #pragma unroll
        for (int j = 0; j < 4; ++j) acc[i][j] = (f32x4){0.f, 0.f, 0.f, 0.f};

    stage(0, kb);
    int cur = 0;
    for (int k0 = kb; k0 < ke; k0 += 32) {
        const bool more = (k0 + 32) < ke;
        if (more) { stage(cur ^ 1, k0 + 32); wait_vm<NL>(); }
        else      { wait_vm<0>(); }
        __builtin_amdgcn_s_barrier();
        __builtin_amdgcn_sched_barrier(0);
        bf16x8 af[4], bfr[4];
        #pragma unroll
        for (int i = 0; i < 4; ++i)
            af[i] = *(const bf16x8*)(&As[cur][(wm + 16 * i + frow) * 32 + fq * 8]);
        #pragma unroll
        for (int j = 0; j < 4; ++j)
            bfr[j] = *(const bf16x8*)(&Bs[cur][(wn + 16 * j + frow) * 32 + fq * 8]);
        asm volatile("s_waitcnt lgkmcnt(0)" ::: "memory");
        __builtin_amdgcn_sched_barrier(0);
        __builtin_amdgcn_s_barrier();
        #pragma unroll
        for (int i = 0; i < 4; ++i)
            #pragma unroll
            for (int j = 0; j < 4; ++j)
                acc[i][j] = __builtin_amdgcn_mfma_f32_16x16x32_bf16(
                    af[i], bfr[j], acc[i][j], 0, 0, 0);
        cur ^= 1;
    }
    float* Pz = P + (size_t)blockIdx.z * M * N;
    #pragma unroll
    for (int i = 0; i < 4; ++i) {
        #pragma unroll
        for (int j = 0; j < 4; ++j) {
            #pragma unroll
            for (int r = 0; r < 4; ++r) {
                int row = bm + wm + 16 * i + fq * 4 + r;
                int col = bn + wn + 16 * j + frow;
                Pz[(size_t)row * N + col] = acc[i][j][r];
            }
        }
    }
}

// x[i] += P0[i] + P1[i] + P2[i] + P3[i]  (float4 vectorized; n4 = n/4)
__global__ __launch_bounds__(256) void reduce4_kernel(
    const float* __restrict__ P, float* __restrict__ x, int n4)
{
    int i = blockIdx.x * 256 + threadIdx.x;
    if (i >= n4) return;
    const int n = n4 << 2;
    float4 a  = ((const float4*)x)[i];
    float4 p0 = ((const float4*)P)[i];
    float4 p1 = ((const float4*)(P + (size_t)n))[i];
    float4 p2 = ((const float4*)(P + (size_t)2 * n))[i];
    float4 p3 = ((const float4*)(P + (size_t)3 * n))[i];
    a.x += p0.x + p1.x + p2.x + p3.x;
    a.y += p0.y + p1.y + p2.y + p3.y;
    a.z += p0.z + p1.z + p2.z + p3.z;
    a.w += p0.w + p1.w + p2.w + p3.w;
    ((float4*)x)[i] = a;
}

// ---------------- RMS norm fp32->fp32 ----------------
__global__ __launch_bounds__(256) void rms_kernel(
    const float* __restrict__ in, const float* __restrict__ w,
    float* __restrict__ out)
{
    int row = blockIdx.x;
    const float* xr = in + (size_t)row * HID;
    float ss = 0.f;
    for (int i = threadIdx.x; i < HID; i += 256) { float v = xr[i]; ss += v * v; }
    #pragma unroll
    for (int off = 32; off > 0; off >>= 1) ss += __shfl_down(ss, off, 64);
    __shared__ float red[4];
    int wid = threadIdx.x >> 6;
    if ((threadIdx.x & 63) == 0) red[wid] = ss;
    __syncthreads();
    if (threadIdx.x == 0)
        red[0] = rsqrtf((red[0] + red[1] + red[2] + red[3]) / HID + EPSV);
    __syncthreads();
    float rs = red[0];
    for (int i = threadIdx.x; i < HID; i += 256)
        out[(size_t)row * HID + i] = xr[i] * rs * w[i];
}

// ---------------- RMS norm fp32->bf16 ----------------
__global__ __launch_bounds__(256) void rms_bf_kernel(
    const float* __restrict__ in, const float* __restrict__ w,
    ushort* __restrict__ out)
{
    int row = blockIdx.x;
    const float* xr = in + (size_t)row * HID;
    float ss = 0.f;
    for (int i = threadIdx.x; i < HID; i += 256) { float v = xr[i]; ss += v * v; }
    #pragma unroll
    for (int off = 32; off > 0; off >>= 1) ss += __shfl_down(ss, off, 64);
    __shared__ float red[4];
    int wid = threadIdx.x >> 6;
    if ((threadIdx.x & 63) == 0) red[wid] = ss;
    __syncthreads();
    if (threadIdx.x == 0)
        red[0] = rsqrtf((red[0] + red[1] + red[2] + red[3]) / HID + EPSV);
    __syncthreads();
    float rs = red[0];
    for (int i = threadIdx.x; i < HID; i += 256)
        out[(size_t)row * HID + i] = f2bf(xr[i] * rs * w[i]);
}

// ---------------- RoPE tables ----------------
__global__ void rope_tab_kernel(float* __restrict__ cs, float* __restrict__ sn)
{
    int s = blockIdx.x; int j = threadIdx.x; // 32 threads
    int h, w;
    if (s < S0) { h = s >> 5; w = s & 31; }
    else { int t = s - S0; h = t >> 4; w = t & 15; }
    float f;
    if (j < 16) f = (float)h * powf(10000.f, -(4.f * j) / 64.f);
    else        f = (float)w * powf(10000.f, -(4.f * (j - 16) + 2.f) / 64.f);
    cs[s * 32 + j] = cosf(f);
    sn[s * 32 + j] = sinf(f);
}

// ---------------- RoPE q,k fp32 -> bf16 qkb[1536][2048] ----------------
__global__ __launch_bounds__(256) void rope_bf_kernel(
    const float* __restrict__ qkv, ushort* __restrict__ qkb,
    const float* __restrict__ cs, const float* __restrict__ sn)
{
    int idx = blockIdx.x * 256 + threadIdx.x;   // S_TOT*2048
    int s = idx >> 11, c = idx & 2047;
    int part = c >> 10, cc = c & 1023;
    int hh = cc >> 6, d = cc & 63, j = d & 31;
    size_t base = (size_t)s * QKVS + part * 1024 + hh * HD;
    float xa = qkv[base + j], xb = qkv[base + 32 + j];
    float cv = cs[s * 32 + j], sv = sn[s * 32 + j];
    float out = (d < 32) ? (xa * cv - xb * sv) : (xb * cv + xa * sv);
    qkb[idx] = f2bf(out);
}

// ---------------- V transpose fp32 qkv -> bf16 vT[head][d][s] ----------------
__global__ __launch_bounds__(256) void vtrans_kernel(
    const float* __restrict__ qkv, ushort* __restrict__ vT)
{
    __shared__ float T[64][65];
    int st = blockIdx.x;   // s-tile (24)
    int hh = blockIdx.y;   // head
    int s0 = st << 6;
    int t = threadIdx.x;
    #pragma unroll
    for (int i = 0; i < 16; i += 4) {
        int u = t + ((i >> 2) << 8);     // 4 iters of 256 -> 1024 float4 units
        int r = u >> 4, c4 = (u & 15) << 2;
        float4 v = *(const float4*)(qkv + (size_t)(s0 + r) * QKVS + 2048 + hh * HD + c4);
        T[r][c4 + 0] = v.x; T[r][c4 + 1] = v.y; T[r][c4 + 2] = v.z; T[r][c4 + 3] = v.w;
    }
    __syncthreads();
    int d = t >> 2, sg = (t & 3) << 4;
    ushort buf[16];
    #pragma unroll
    for (int j = 0; j < 16; ++j) buf[j] = f2bf(T[sg + j][d]);
    ushort* dst = vT + ((size_t)hh * HD + d) * S_TOT + s0 + sg;
    *(u16x8*)dst = *(u16x8*)buf;
    *(u16x8*)(dst + 8) = *(u16x8*)(buf + 8);
}

// ---------------- MFMA flash attention ----------------
// block = (q-tile of 64, head); 4 waves x 16 q-rows; k-tiles of 64 keys.
// Ks[key][d] pitch 72, Vt[d][key] pitch 72, Ps[wave][q][key] pitch 72 (all bf16).
__global__ __launch_bounds__(256) void flash_mfma_kernel(
    const ushort* __restrict__ qkb, const ushort* __restrict__ vT,
    ushort* __restrict__ o)
{
    __shared__ ushort Ks[64 * 72];
    __shared__ ushort Vt[64 * 72];
    __shared__ ushort Ps[4 * 16 * 72];
    int tile = blockIdx.x;
    int hh = blockIdx.y;
    int segStart, q0, nkt;
    if (tile < 16) { segStart = 0; q0 = tile << 6; nkt = 16; }
    else { segStart = S0; q0 = S0 + ((tile - 16) << 6); nkt = 8; }
    const int t = threadIdx.x;
    const int wave = t >> 6, lane = t & 63;
    const int c = lane & 15, fq = lane >> 4;
    const int wq = wave << 4;
    ushort* Pw = Ps + wave * 16 * 72;

    // Q fragments direct from global (A-operand layout), reused across all k-tiles
    bf16x8 qf[2];
    #pragma unroll
    for (int ks = 0; ks < 2; ++ks)
        qf[ks] = *(const bf16x8*)(qkb + (size_t)(q0 + wq + c) * QKS + hh * HD + ks * 32 + fq * 8);

    float m_i[4], l_i[4];
    f32x4 accO[4];
    #pragma unroll
    for (int r = 0; r < 4; ++r) { m_i[r] = -1e30f; l_i[r] = 0.f; }
    #pragma unroll
    for (int nt = 0; nt < 4; ++nt) accO[nt] = (f32x4){0.f, 0.f, 0.f, 0.f};

    for (int kt = 0; kt < nkt; ++kt) {
        int kbase = segStart + (kt << 6);
        __syncthreads();
        // stage K rows (bf16, row-major) and Vt rows (bf16, d-major from global vT)
        #pragma unroll
        for (int i = 0; i < 2; ++i) {
            int u = t + (i << 8);            // 512 ushort8 units
            int r = u >> 3, c8 = (u & 7) << 3;
            u16x8 kv = *(const u16x8*)(qkb + (size_t)(kbase + r) * QKS + 1024 + hh * HD + c8);
            *(u16x8*)(Ks + r * 72 + c8) = kv;
            u16x8 vv = *(const u16x8*)(vT + ((size_t)hh * HD + r) * S_TOT + kbase + c8);
            *(u16x8*)(Vt + r * 72 + c8) = vv;
        }
        __syncthreads();

        // QK^T: scores C[q=fq*4+r][key=nt*16+c]
        f32x4 acc[4];
        #pragma unroll
        for (int nt = 0; nt < 4; ++nt) acc[nt] = (f32x4){0.f, 0.f, 0.f, 0.f};
        #pragma unroll
        for (int ks = 0; ks < 2; ++ks) {
            #pragma unroll
            for (int nt = 0; nt < 4; ++nt) {
                bf16x8 bfr = *(const bf16x8*)(Ks + (nt * 16 + c) * 72 + ks * 32 + fq * 8);
                acc[nt] = __builtin_amdgcn_mfma_f32_16x16x32_bf16(qf[ks], bfr, acc[nt], 0, 0, 0);
            }
        }

        // online softmax (per q-row r), P -> LDS (bf16, A-operand layout)
        #pragma unroll
        for (int r = 0; r < 4; ++r) {
            float s0v = acc[0][r] * SCALEV, s1v = acc[1][r] * SCALEV;
            float s2v = acc[2][r] * SCALEV, s3v = acc[3][r] * SCALEV;
            float rm = fmaxf(fmaxf(s0v, s1v), fmaxf(s2v, s3v));
            #pragma unroll
            for (int msk = 1; msk < 16; msk <<= 1)
                rm = fmaxf(rm, __shfl_xor(rm, msk, 64));
            float mn = fmaxf(m_i[r], rm);
            float al = __expf(m_i[r] - mn);
            float p0 = __expf(s0v - mn), p1 = __expf(s1v - mn);
            float p2 = __expf(s2v - mn), p3 = __expf(s3v - mn);
            float rs = p0 + p1 + p2 + p3;
            #pragma unroll
            for (int msk = 1; msk < 16; msk <<= 1)
                rs += __shfl_xor(rs, msk, 64);
            l_i[r] = l_i[r] * al + rs;
            m_i[r] = mn;
            #pragma unroll
            for (int nt = 0; nt < 4; ++nt) accO[nt][r] *= al;
            int qrow = (fq << 2) + r;
            Pw[qrow * 72 + 0  + c] = f2bf(p0);
            Pw[qrow * 72 + 16 + c] = f2bf(p1);
            Pw[qrow * 72 + 32 + c] = f2bf(p2);
            Pw[qrow * 72 + 48 + c] = f2bf(p3);
        }

        // PV: O[q][d=nt*16+c] += P[q][key] * V[key][d]
        #pragma unroll
        for (int ks = 0; ks < 2; ++ks) {
            bf16x8 pa = *(const bf16x8*)(Pw + c * 72 + ks * 32 + fq * 8);
            #pragma unroll
            for (int nt = 0; nt < 4; ++nt) {
                bf16x8 bv = *(const bf16x8*)(Vt + (nt * 16 + c) * 72 + ks * 32 + fq * 8);
                accO[nt] = __builtin_amdgcn_mfma_f32_16x16x32_bf16(pa, bv, accO[nt], 0, 0, 0);
            }
        }
    }

    // epilogue
    #pragma unroll
    for (int r = 0; r < 4; ++r) {
        float inv = 1.f / l_i[r];
        int row = q0 + wq + (fq << 2) + r;
        #pragma unroll
        for (int nt = 0; nt < 4; ++nt)
            o[(size_t)row * HID + hh * HD + nt * 16 + c] = f2bf(accO[nt][r] * inv);
    }
}

// ---------------- SiLU(gate)*up from fused bf16 [S][8192] -> bf16 [S][4096] ----------------
__global__ __launch_bounds__(256) void silu_mul_bf_kernel(
    const ushort* __restrict__ gu, ushort* __restrict__ gb)
{
    int i = blockIdx.x * 256 + threadIdx.x;   // S_TOT*INTER
    int s = i >> 12, cc = i & 4095;
    float x = bf2f(gu[(size_t)s * 8192 + cc]);
    float u = bf2f(gu[(size_t)s * 8192 + 4096 + cc]);
    float sg = 1.f / (1.f + __expf(-x));
    gb[i] = f2bf(x * sg * u);
}

// ---------------- copy to out ----------------
__global__ __launch_bounds__(256) void copy_kernel(
    const float* __restrict__ src, float* __restrict__ dst, int n)
{
    int i = blockIdx.x * 256 + threadIdx.x;
    if (i < n) dst[i] = src[i];
}

extern "C" void kernel_launch(void* const* d_in, const int* in_sizes, int n_in,
                              void* d_out, int out_size, void* d_ws, size_t ws_size,
                              hipStream_t stream)
{
    const float* img0        = (const float*)d_in[0];
    const float* img1        = (const float*)d_in[1];
    const float* conv_w      = (const float*)d_in[2];
    const float* ln_pre_w    = (const float*)d_in[3];
    const float* attn_norm_w = (const float*)d_in[4];
    const float* q_w         = (const float*)d_in[5];
    const float* k_w         = (const float*)d_in[6];
    const float* v_w         = (const float*)d_in[7];
    const float* o_w         = (const float*)d_in[8];
    const float* ffn_norm_w  = (const float*)d_in[9];
    const float* gate_w      = (const float*)d_in[10];
    const float* up_w        = (const float*)d_in[11];
    const float* down_w      = (const float*)d_in[12];

    char* p = (char*)d_ws;
    float* x    = (float*)p;   p += (size_t)1572864 * 4;   // [1536][1024]
    float* qkv  = (float*)p;   p += (size_t)4718592 * 4;   // [1536][3072]
    float* cs   = (float*)p;   p += (size_t)49152 * 4;
    float* sn   = (float*)p;   p += (size_t)49152 * 4;
    ushort* qkb = (ushort*)p;  p += (size_t)3145728 * 2;   // [1536][2048] rope'd q|k bf16
    ushort* vTb = (ushort*)p;  p += (size_t)1572864 * 2;   // [16][64][1536] V^T bf16
    ushort* hnb = (ushort*)p;  p += (size_t)1572864 * 2;   // [1536][1024]
    ushort* obb = (ushort*)p;  p += (size_t)1572864 * 2;   // [1536][1024]
    ushort* gub = (ushort*)p;  p += (size_t)12582912 * 2;  // [1536][8192]
    ushort* gb  = (ushort*)p;  p += (size_t)6291456 * 2;   // [1536][4096]
    ushort* Pb  = (ushort*)p;  p += (size_t)1179648 * 2;   // [1536][768]
    ushort* cvb = (ushort*)p;  p += (size_t)786432 * 2;    // conv_w bf16
    ushort* wbuf= (ushort*)p;  p += (size_t)16777216 * 2;  // per-layer weights

    ushort* wqkv = wbuf;                 // [3072][1024]
    ushort* wo   = wbuf + 3145728;       // [1024][1024]
    ushort* wgu  = wbuf + 4194304;       // [8192][1024]
    ushort* wdn  = wbuf + 12582912;      // [1024][4096]

    // split-K partial slabs (4 x [1536][1024] f32 = 25.2 MB) overlaid on gub:
    // gub is only live between the gate/up GEMM and silu_mul; both sk GEMMs +
    // reductions run strictly outside that window on the same stream.
    float* skP = (float*)gub;

    dim3 blk(256);

    cvt_kernel<<<768, blk, 0, stream>>>(conv_w, cvb, 786432 / 4);
    im2col_kernel<<<S_TOT, blk, 0, stream>>>(img0, img1, Pb);
    gemm2p<64, 64, false><<<dim3(24, 16), blk, 0, stream>>>(
        Pb, cvb, x, S_TOT, HID, KCONV);
    rms_kernel<<<S_TOT, blk, 0, stream>>>(x, ln_pre_w, x);
    rope_tab_kernel<<<S_TOT, 32, 0, stream>>>(cs, sn);

    for (int l = 0; l < NLAYERS; ++l) {
        cvt_layer_kernel<<<16384, blk, 0, stream>>>(
            q_w + (size_t)l * 1048576, k_w + (size_t)l * 1048576,
            v_w + (size_t)l * 1048576, o_w + (size_t)l * 1048576,
            gate_w + (size_t)l * 4194304, up_w + (size_t)l * 4194304,
            down_w + (size_t)l * 4194304, wbuf);

        rms_bf_kernel<<<S_TOT, blk, 0, stream>>>(x, attn_norm_w + (size_t)l * HID, hnb);
        gemm2p<128, 128, false><<<dim3(12, 24), blk, 0, stream>>>(
            hnb, wqkv, qkv, S_TOT, QKVS, HID);
        rope_bf_kernel<<<(S_TOT * QKS) / 256, blk, 0, stream>>>(qkv, qkb, cs, sn);
        vtrans_kernel<<<dim3(24, HEADS), blk, 0, stream>>>(qkv, vTb);
        flash_mfma_kernel<<<dim3(24, HEADS), blk, 0, stream>>>(qkb, vTb, obb);
        // o-projection: partials then x += sum (residual already in x)
        gemm2p_sk<4><<<dim3(12, 8, 4), blk, 0, stream>>>(
            obb, wo, skP, S_TOT, HID, HID);
        reduce4_kernel<<<1536, blk, 0, stream>>>(skP, x, S_TOT * HID / 4);
        rms_bf_kernel<<<S_TOT, blk, 0, stream>>>(x, ffn_norm_w + (size_t)l * HID, hnb);
        gemm2p<128, 128, true><<<dim3(12, 64), blk, 0, stream>>>(
            hnb, wgu, gub, S_TOT, 2 * INTER, HID);
        silu_mul_bf_kernel<<<(S_TOT * INTER) / 256, blk, 0, stream>>>(gub, gb);
        // down-projection: split-K=4 (kc=1024, 32 K-steps), partials + reduce
        gemm2p_sk<4><<<dim3(12, 8, 4), blk, 0, stream>>>(
            gb, wdn, skP, S_TOT, HID, INTER);
        reduce4_kernel<<<1536, blk, 0, stream>>>(skP, x, S_TOT * HID / 4);
    }
    copy_kernel<<<(S_TOT * HID) / 256, blk, 0, stream>>>(x, (float*)d_out, S_TOT * HID);
}

// Round 3
// 927.871 us; speedup vs baseline: 1.2434x; 1.0774x over previous
//
#include <hip/hip_runtime.h>
#include <hip/hip_bf16.h>
#include <math.h>

#define S_TOT 1536
#define S0    1024
#define HID   1024
#define HEADS 16
#define HD    64
#define INTER 4096
#define NLAYERS 4
#define KCONV 768
#define EPSV  1e-5f
#define SCALEV 0.125f
#define QKS   2048   // fused rope'd q|k bf16 row stride

typedef __attribute__((ext_vector_type(8))) __bf16 bf16x8;
typedef __attribute__((ext_vector_type(8))) unsigned short u16x8;
typedef __attribute__((ext_vector_type(4))) float f32x4;
typedef __attribute__((address_space(1))) void gvoid;
typedef __attribute__((address_space(3))) void lvoid;

__device__ __forceinline__ ushort f2bf(float f) {
    union { float f; unsigned u; } v; v.f = f;
    unsigned u = v.u;
    return (ushort)((u + 0x7FFFu + ((u >> 16) & 1u)) >> 16);
}
__device__ __forceinline__ float bf2f(ushort b) {
    union { unsigned u; float f; } v; v.u = ((unsigned)b) << 16;
    return v.f;
}

// counted vmcnt wait with compile-time immediate
template<int N> __device__ __forceinline__ void wait_vm() {
    if constexpr (N == 0)      asm volatile("s_waitcnt vmcnt(0)" ::: "memory");
    else if constexpr (N == 2) asm volatile("s_waitcnt vmcnt(2)" ::: "memory");
    else if constexpr (N == 4) asm volatile("s_waitcnt vmcnt(4)" ::: "memory");
    else if constexpr (N == 8) asm volatile("s_waitcnt vmcnt(8)" ::: "memory");
    else                       asm volatile("s_waitcnt vmcnt(0)" ::: "memory");
}

// ---------------- weight converts ----------------
__global__ __launch_bounds__(256) void cvt_kernel(
    const float* __restrict__ src, ushort* __restrict__ dst, int n4)
{
    int i = blockIdx.x * 256 + threadIdx.x;
    if (i < n4) {
        float4 v = ((const float4*)src)[i];
        ushort4 o;
        o.x = f2bf(v.x); o.y = f2bf(v.y); o.z = f2bf(v.z); o.w = f2bf(v.w);
        ((ushort4*)dst)[i] = o;
    }
}

// fused per-layer weight convert: dst = [qkv(3M) | o(1M) | gu-interleaved(8M) | down(4M)]
// gate/up rows interleaved in 16-row blocks: rows [32b..32b+15] = gate chans [16b..16b+15],
// rows [32b+16..32b+31] = up of the same channels. This makes (gate[c], up[c]) land in the
// SAME LANE of the MFMA C-fragment (j even / j odd 16-col blocks) for the fused-silu epilogue.
__global__ __launch_bounds__(256) void cvt_layer_kernel(
    const float* __restrict__ qw, const float* __restrict__ kw,
    const float* __restrict__ vw, const float* __restrict__ ow,
    const float* __restrict__ gw, const float* __restrict__ uw,
    const float* __restrict__ dw, ushort* __restrict__ dst)
{
    int i = blockIdx.x * 256 + threadIdx.x;   // 4-elem group, 4M groups
    int e = i << 2;
    const float* src; int off; size_t de;
    if      (e < (1  << 20)) { src = qw; off = e;             de = e; }
    else if (e < (2  << 20)) { src = kw; off = e - (1 << 20); de = e; }
    else if (e < (3  << 20)) { src = vw; off = e - (2 << 20); de = e; }
    else if (e < (4  << 20)) { src = ow; off = e - (3 << 20); de = e; }
    else if (e < (8  << 20)) {
        src = gw; off = e - (4 << 20);
        int chan = off >> 10, col = off & 1023;
        de = (size_t)(4 << 20) + (size_t)(((chan >> 4) << 5) + (chan & 15)) * 1024 + col;
    }
    else if (e < (12 << 20)) {
        src = uw; off = e - (8 << 20);
        int chan = off >> 10, col = off & 1023;
        de = (size_t)(4 << 20) + (size_t)(((chan >> 4) << 5) + 16 + (chan & 15)) * 1024 + col;
    }
    else                     { src = dw; off = e - (12 << 20); de = e; }
    float4 v = *(const float4*)(src + off);
    ushort4 o;
    o.x = f2bf(v.x); o.y = f2bf(v.y); o.z = f2bf(v.z); o.w = f2bf(v.w);
    *(ushort4*)(dst + de) = o;
}

// ---------------- im2col (bf16 out) ----------------
__global__ __launch_bounds__(256) void im2col_kernel(
    const float* __restrict__ img0, const float* __restrict__ img1,
    ushort* __restrict__ P)
{
    int s = blockIdx.x;
    const float* img; int W, ph, pw;
    if (s < S0) { img = img0; W = 512; ph = s >> 5; pw = s & 31; }
    else { int t = s - S0; img = img1; W = 256; ph = t >> 4; pw = t & 15; }
    for (int k = threadIdx.x; k < KCONV; k += 256) {
        int c = k >> 8; int r = k & 255; int y = r >> 4; int x = r & 15;
        P[(size_t)s * KCONV + k] =
            f2bf(img[(size_t)c * 512 * W + (size_t)(ph * 16 + y) * W + (pw * 16 + x)]);
    }
}

// ============ 2-phase double-buffered K-loop (shared macro-body) ============
// Issues next tile's global_load_lds BEFORE current compute; counted vmcnt so
// loads stay in flight across barriers (never drained to 0 mid-loop).
#define GEMM2P_CORE(BM_, BN_, NLA_, NLB_)                                        \
    auto stage = [&](int b, int k0) {                                            \
        _Pragma("unroll")                                                        \
        for (int i_ = 0; i_ < NLA_; ++i_) {                                      \
            int idx = t + i_ * 256;                                              \
            int r_ = idx >> 2, c8_ = (idx & 3) << 3;                             \
            __builtin_amdgcn_global_load_lds(                                    \
                (gvoid*)(A + (size_t)(bm + r_) * K + k0 + c8_),                  \
                (lvoid*)(&As[b][idx * 8]), 16, 0, 0);                            \
        }                                                                        \
        _Pragma("unroll")                                                        \
        for (int i_ = 0; i_ < NLB_; ++i_) {                                      \
            int idx = t + i_ * 256;                                              \
            int r_ = idx >> 2, c8_ = (idx & 3) << 3;                             \
            __builtin_amdgcn_global_load_lds(                                    \
                (gvoid*)(B + (size_t)(bn + r_) * K + k0 + c8_),                  \
                (lvoid*)(&Bs[b][idx * 8]), 16, 0, 0);                            \
        }                                                                        \
    };

// ---------------- generic 2-phase GEMM: C[M][N] = A[M][K] * B[N][K]^T ----------------
template<int BM, int BN, bool OUT_BF16>
__global__ __launch_bounds__(256) void gemm2p(
    const ushort* __restrict__ A, const ushort* __restrict__ B,
    void* __restrict__ Cout, int M, int N, int K)
{
    constexpr int WMT = BM / 32, WNT = BN / 32;
    constexpr int NLA = (BM * 32) / (8 * 256);
    constexpr int NLB = (BN * 32) / (8 * 256);
    constexpr int NL  = NLA + NLB;
    __shared__ ushort As[2][BM * 32];
    __shared__ ushort Bs[2][BN * 32];
    const int t = threadIdx.x;
    const int bm = blockIdx.x * BM, bn = blockIdx.y * BN;
    const int wave = t >> 6, lane = t & 63;
    const int wm = (wave & 1) * (BM / 2), wn = (wave >> 1) * (BN / 2);
    const int frow = lane & 15, fq = lane >> 4;
    GEMM2P_CORE(BM, BN, NLA, NLB)

    f32x4 acc[WMT][WNT];
    #pragma unroll
    for (int i = 0; i < WMT; ++i)
        #pragma unroll
        for (int j = 0; j < WNT; ++j) acc[i][j] = (f32x4){0.f, 0.f, 0.f, 0.f};

    stage(0, 0);
    int cur = 0;
    for (int k0 = 0; k0 < K; k0 += 32) {
        const bool more = (k0 + 32) < K;
        if (more) { stage(cur ^ 1, k0 + 32); wait_vm<NL>(); }
        else      { wait_vm<0>(); }
        __builtin_amdgcn_s_barrier();
        __builtin_amdgcn_sched_barrier(0);
        bf16x8 af[WMT], bfr[WNT];
        #pragma unroll
        for (int i = 0; i < WMT; ++i)
            af[i] = *(const bf16x8*)(&As[cur][(wm + 16 * i + frow) * 32 + fq * 8]);
        #pragma unroll
        for (int j = 0; j < WNT; ++j)
            bfr[j] = *(const bf16x8*)(&Bs[cur][(wn + 16 * j + frow) * 32 + fq * 8]);
        asm volatile("s_waitcnt lgkmcnt(0)" ::: "memory");
        __builtin_amdgcn_sched_barrier(0);
        __builtin_amdgcn_s_barrier();
        #pragma unroll
        for (int i = 0; i < WMT; ++i)
            #pragma unroll
            for (int j = 0; j < WNT; ++j)
                acc[i][j] = __builtin_amdgcn_mfma_f32_16x16x32_bf16(
                    af[i], bfr[j], acc[i][j], 0, 0, 0);
        cur ^= 1;
    }
    #pragma unroll
    for (int i = 0; i < WMT; ++i) {
        #pragma unroll
        for (int j = 0; j < WNT; ++j) {
            #pragma unroll
            for (int r = 0; r < 4; ++r) {
                int row = bm + wm + 16 * i + fq * 4 + r;
                int col = bn + wn + 16 * j + frow;
                float vv = acc[i][j][r];
                if (OUT_BF16) ((ushort*)Cout)[(size_t)row * N + col] = f2bf(vv);
                else          ((float*)Cout)[(size_t)row * N + col] = vv;
            }
        }
    }
}

// ---------------- qkv GEMM (128x128) with fused RoPE epilogue ----------------
// cols [0,2048): rope'd bf16 -> qkb[row][col]; cols [2048,3072): bf16 -> vb[row][col-2048].
// RoPE pairs (d, d+32) are fragment cols (16j+frow, j) and (j+2): same lane, no shuffle.
__global__ __launch_bounds__(256) void gemm2p_qkv(
    const ushort* __restrict__ A, const ushort* __restrict__ B,
    ushort* __restrict__ qkb, ushort* __restrict__ vb,
    const float* __restrict__ cs, const float* __restrict__ sn, int K)
{
    constexpr int BM = 128, BN = 128;
    __shared__ ushort As[2][BM * 32];
    __shared__ ushort Bs[2][BN * 32];
    const int t = threadIdx.x;
    const int bm = blockIdx.x * BM, bn = blockIdx.y * BN;
    const int wave = t >> 6, lane = t & 63;
    const int wm = (wave & 1) * 64, wn = (wave >> 1) * 64;
    const int frow = lane & 15, fq = lane >> 4;
    GEMM2P_CORE(BM, BN, 2, 2)

    f32x4 acc[4][4];
    #pragma unroll
    for (int i = 0; i < 4; ++i)
        #pragma unroll
        for (int j = 0; j < 4; ++j) acc[i][j] = (f32x4){0.f, 0.f, 0.f, 0.f};

    stage(0, 0);
    int cur = 0;
    for (int k0 = 0; k0 < K; k0 += 32) {
        const bool more = (k0 + 32) < K;
        if (more) { stage(cur ^ 1, k0 + 32); wait_vm<4>(); }
        else      { wait_vm<0>(); }
        __builtin_amdgcn_s_barrier();
        __builtin_amdgcn_sched_barrier(0);
        bf16x8 af[4], bfr[4];
        #pragma unroll
        for (int i = 0; i < 4; ++i)
            af[i] = *(const bf16x8*)(&As[cur][(wm + 16 * i + frow) * 32 + fq * 8]);
        #pragma unroll
        for (int j = 0; j < 4; ++j)
            bfr[j] = *(const bf16x8*)(&Bs[cur][(wn + 16 * j + frow) * 32 + fq * 8]);
        asm volatile("s_waitcnt lgkmcnt(0)" ::: "memory");
        __builtin_amdgcn_sched_barrier(0);
        __builtin_amdgcn_s_barrier();
        #pragma unroll
        for (int i = 0; i < 4; ++i)
            #pragma unroll
            for (int j = 0; j < 4; ++j)
                acc[i][j] = __builtin_amdgcn_mfma_f32_16x16x32_bf16(
                    af[i], bfr[j], acc[i][j], 0, 0, 0);
        cur ^= 1;
    }
    const int colbase = bn + wn;          // 64-aligned; q/k/v section uniform per wave-half
    const int part = colbase >> 10;       // 0=q, 1=k, 2=v
    if (part < 2) {
        #pragma unroll
        for (int i = 0; i < 4; ++i) {
            #pragma unroll
            for (int r = 0; r < 4; ++r) {
                int row = bm + wm + 16 * i + fq * 4 + r;
                float cv0 = cs[row * 32 + frow],      sv0 = sn[row * 32 + frow];
                float cv1 = cs[row * 32 + 16 + frow], sv1 = sn[row * 32 + 16 + frow];
                float xa0 = acc[i][0][r], xa1 = acc[i][1][r];
                float xb0 = acc[i][2][r], xb1 = acc[i][3][r];
                ushort* dst = qkb + (size_t)row * QKS + (part << 10) + (colbase & 1023) + frow;
                dst[0]  = f2bf(xa0 * cv0 - xb0 * sv0);
                dst[16] = f2bf(xa1 * cv1 - xb1 * sv1);
                dst[32] = f2bf(xb0 * cv0 + xa0 * sv0);
                dst[48] = f2bf(xb1 * cv1 + xa1 * sv1);
            }
        }
    } else {
        #pragma unroll
        for (int i = 0; i < 4; ++i)
            #pragma unroll
            for (int j = 0; j < 4; ++j)
                #pragma unroll
                for (int r = 0; r < 4; ++r) {
                    int row = bm + wm + 16 * i + fq * 4 + r;
                    vb[(size_t)row * 1024 + (colbase & 1023) + 16 * j + frow] =
                        f2bf(acc[i][j][r]);
                }
    }
}

// ---------------- gate/up GEMM (128x128, gu-interleaved weights) + fused SiLU ----------------
// abs 16-col block even = gate, odd = up of same channels -> pair is same-lane (j=2jp, 2jp+1).
__global__ __launch_bounds__(256) void gemm2p_gu(
    const ushort* __restrict__ A, const ushort* __restrict__ B,
    ushort* __restrict__ gb, int K)
{
    constexpr int BM = 128, BN = 128;
    __shared__ ushort As[2][BM * 32];
    __shared__ ushort Bs[2][BN * 32];
    const int t = threadIdx.x;
    const int bm = blockIdx.x * BM, bn = blockIdx.y * BN;
    const int wave = t >> 6, lane = t & 63;
    const int wm = (wave & 1) * 64, wn = (wave >> 1) * 64;
    const int frow = lane & 15, fq = lane >> 4;
    GEMM2P_CORE(BM, BN, 2, 2)

    f32x4 acc[4][4];
    #pragma unroll
    for (int i = 0; i < 4; ++i)
        #pragma unroll
        for (int j = 0; j < 4; ++j) acc[i][j] = (f32x4){0.f, 0.f, 0.f, 0.f};

    stage(0, 0);
    int cur = 0;
    for (int k0 = 0; k0 < K; k0 += 32) {
        const bool more = (k0 + 32) < K;
        if (more) { stage(cur ^ 1, k0 + 32); wait_vm<4>(); }
        else      { wait_vm<0>(); }
        __builtin_amdgcn_s_barrier();
        __builtin_amdgcn_sched_barrier(0);
        bf16x8 af[4], bfr[4];
        #pragma unroll
        for (int i = 0; i < 4; ++i)
            af[i] = *(const bf16x8*)(&As[cur][(wm + 16 * i + frow) * 32 + fq * 8]);
        #pragma unroll
        for (int j = 0; j < 4; ++j)
            bfr[j] = *(const bf16x8*)(&Bs[cur][(wn + 16 * j + frow) * 32 + fq * 8]);
        asm volatile("s_waitcnt lgkmcnt(0)" ::: "memory");
        __builtin_amdgcn_sched_barrier(0);
        __builtin_amdgcn_s_barrier();
        #pragma unroll
        for (int i = 0; i < 4; ++i)
            #pragma unroll
            for (int j = 0; j < 4; ++j)
                acc[i][j] = __builtin_amdgcn_mfma_f32_16x16x32_bf16(
                    af[i], bfr[j], acc[i][j], 0, 0, 0);
        cur ^= 1;
    }
    #pragma unroll
    for (int i = 0; i < 4; ++i) {
        #pragma unroll
        for (int jp = 0; jp < 2; ++jp) {
            int chan = ((bn + wn) >> 1) + jp * 16 + frow;
            #pragma unroll
            for (int r = 0; r < 4; ++r) {
                int row = bm + wm + 16 * i + fq * 4 + r;
                float g = acc[i][2 * jp][r], u = acc[i][2 * jp + 1][r];
                float sg = 1.f / (1.f + __expf(-g));
                gb[(size_t)row * INTER + chan] = f2bf(g * sg * u);
            }
        }
    }
}

// ============ 2-phase split-K GEMM: writes f32 partial slabs (no atomics) ============
template<int SPLITK>
__global__ __launch_bounds__(256) void gemm2p_sk(
    const ushort* __restrict__ A, const ushort* __restrict__ B,
    float* __restrict__ P, int M, int N, int K)
{
    constexpr int BM = 128, BN = 128;
    __shared__ ushort As[2][BM * 32];
    __shared__ ushort Bs[2][BN * 32];
    const int t = threadIdx.x;
    const int bm = blockIdx.x * BM, bn = blockIdx.y * BN;
    const int kc = K / SPLITK;
    const int kb = blockIdx.z * kc, ke = kb + kc;
    const int wave = t >> 6, lane = t & 63;
    const int wm = (wave & 1) * 64, wn = (wave >> 1) * 64;
    const int frow = lane & 15, fq = lane >> 4;
    GEMM2P_CORE(BM, BN, 2, 2)

    f32x4 acc[4][4];
    #pragma unroll
    for (int i = 0; i < 4; ++i)
        #pragma unroll
        for (int j = 0; j < 4; ++j) acc[i][j] = (f32x4){0.f, 0.f, 0.f, 0.f};

    stage(0, kb);
    int cur = 0;
    for (int k0 = kb; k0 < ke; k0 += 32) {
        const bool more = (k0 + 32) < ke;
        if (more) { stage(cur ^ 1, k0 + 32); wait_vm<4>(); }
        else      { wait_vm<0>(); }
        __builtin_amdgcn_s_barrier();
        __builtin_amdgcn_sched_barrier(0);
        bf16x8 af[4], bfr[4];
        #pragma unroll
        for (int i = 0; i < 4; ++i)
            af[i] = *(const bf16x8*)(&As[cur][(wm + 16 * i + frow) * 32 + fq * 8]);
        #pragma unroll
        for (int j = 0; j < 4; ++j)
            bfr[j] = *(const bf16x8*)(&Bs[cur][(wn + 16 * j + frow) * 32 + fq * 8]);
        asm volatile("s_waitcnt lgkmcnt(0)" ::: "memory");
        __builtin_amdgcn_sched_barrier(0);
        __builtin_amdgcn_s_barrier();
        #pragma unroll
        for (int i = 0; i < 4; ++i)
            #pragma unroll
            for (int j = 0; j < 4; ++j)
                acc[i][j] = __builtin_amdgcn_mfma_f32_16x16x32_bf16(
                    af[i], bfr[j], acc[i][j], 0, 0, 0);
        cur ^= 1;
    }
    float* Pz = P + (size_t)blockIdx.z * M * N;
    #pragma unroll
    for (int i = 0; i < 4; ++i) {
        #pragma unroll
        for (int j = 0; j < 4; ++j) {
            #pragma unroll
            for (int r = 0; r < 4; ++r) {
                int row = bm + wm + 16 * i + fq * 4 + r;
                int col = bn + wn + 16 * j + frow;
                Pz[(size_t)row * N + col] = acc[i][j][r];
            }
        }
    }
}

// x[i] += P0[i] + P1[i] + P2[i] + P3[i]  (float4 vectorized; n4 = n/4)
__global__ __launch_bounds__(256) void reduce4_kernel(
    const float* __restrict__ P, float* __restrict__ x, int n4)
{
    int i = blockIdx.x * 256 + threadIdx.x;
    if (i >= n4) return;
    const int n = n4 << 2;
    float4 a  = ((const float4*)x)[i];
    float4 p0 = ((const float4*)P)[i];
    float4 p1 = ((const float4*)(P + (size_t)n))[i];
    float4 p2 = ((const float4*)(P + (size_t)2 * n))[i];
    float4 p3 = ((const float4*)(P + (size_t)3 * n))[i];
    a.x += p0.x + p1.x + p2.x + p3.x;
    a.y += p0.y + p1.y + p2.y + p3.y;
    a.z += p0.z + p1.z + p2.z + p3.z;
    a.w += p0.w + p1.w + p2.w + p3.w;
    ((float4*)x)[i] = a;
}

// ---------------- RMS norm fp32->fp32 ----------------
__global__ __launch_bounds__(256) void rms_kernel(
    const float* __restrict__ in, const float* __restrict__ w,
    float* __restrict__ out)
{
    int row = blockIdx.x;
    const float* xr = in + (size_t)row * HID;
    float ss = 0.f;
    for (int i = threadIdx.x; i < HID; i += 256) { float v = xr[i]; ss += v * v; }
    #pragma unroll
    for (int off = 32; off > 0; off >>= 1) ss += __shfl_down(ss, off, 64);
    __shared__ float red[4];
    int wid = threadIdx.x >> 6;
    if ((threadIdx.x & 63) == 0) red[wid] = ss;
    __syncthreads();
    if (threadIdx.x == 0)
        red[0] = rsqrtf((red[0] + red[1] + red[2] + red[3]) / HID + EPSV);
    __syncthreads();
    float rs = red[0];
    for (int i = threadIdx.x; i < HID; i += 256)
        out[(size_t)row * HID + i] = xr[i] * rs * w[i];
}

// ---------------- RMS norm fp32->bf16 ----------------
__global__ __launch_bounds__(256) void rms_bf_kernel(
    const float* __restrict__ in, const float* __restrict__ w,
    ushort* __restrict__ out)
{
    int row = blockIdx.x;
    const float* xr = in + (size_t)row * HID;
    float ss = 0.f;
    for (int i = threadIdx.x; i < HID; i += 256) { float v = xr[i]; ss += v * v; }
    #pragma unroll
    for (int off = 32; off > 0; off >>= 1) ss += __shfl_down(ss, off, 64);
    __shared__ float red[4];
    int wid = threadIdx.x >> 6;
    if ((threadIdx.x & 63) == 0) red[wid] = ss;
    __syncthreads();
    if (threadIdx.x == 0)
        red[0] = rsqrtf((red[0] + red[1] + red[2] + red[3]) / HID + EPSV);
    __syncthreads();
    float rs = red[0];
    for (int i = threadIdx.x; i < HID; i += 256)
        out[(size_t)row * HID + i] = f2bf(xr[i] * rs * w[i]);
}

// ---------------- RoPE tables ----------------
__global__ void rope_tab_kernel(float* __restrict__ cs, float* __restrict__ sn)
{
    int s = blockIdx.x; int j = threadIdx.x; // 32 threads
    int h, w;
    if (s < S0) { h = s >> 5; w = s & 31; }
    else { int t = s - S0; h = t >> 4; w = t & 15; }
    float f;
    if (j < 16) f = (float)h * powf(10000.f, -(4.f * j) / 64.f);
    else        f = (float)w * powf(10000.f, -(4.f * (j - 16) + 2.f) / 64.f);
    cs[s * 32 + j] = cosf(f);
    sn[s * 32 + j] = sinf(f);
}

// ---------------- V transpose bf16 vb[s][1024] -> bf16 vT[head][d][s] ----------------
__global__ __launch_bounds__(256) void vtrans_bf_kernel(
    const ushort* __restrict__ vb, ushort* __restrict__ vT)
{
    __shared__ ushort T[64][72];
    int st = blockIdx.x;   // s-tile (24)
    int hh = blockIdx.y;   // head
    int s0 = st << 6;
    int t = threadIdx.x;
    #pragma unroll
    for (int i = 0; i < 2; ++i) {
        int u = t + (i << 8);            // 512 u16x8 units
        int r = u >> 3, c8 = (u & 7) << 3;
        u16x8 v = *(const u16x8*)(vb + (size_t)(s0 + r) * 1024 + hh * HD + c8);
        *(u16x8*)(&T[r][c8]) = v;
    }
    __syncthreads();
    int d = t >> 2, sg = (t & 3) << 4;
    ushort buf[16];
    #pragma unroll
    for (int j = 0; j < 16; ++j) buf[j] = T[sg + j][d];
    ushort* dst = vT + ((size_t)hh * HD + d) * S_TOT + s0 + sg;
    *(u16x8*)dst = *(u16x8*)buf;
    *(u16x8*)(dst + 8) = *(u16x8*)(buf + 8);
}

// ---------------- MFMA flash attention ----------------
// block = (q-tile of 64, head); 4 waves x 16 q-rows; k-tiles of 64 keys.
__global__ __launch_bounds__(256) void flash_mfma_kernel(
    const ushort* __restrict__ qkb, const ushort* __restrict__ vT,
    ushort* __restrict__ o)
{
    __shared__ ushort Ks[64 * 72];
    __shared__ ushort Vt[64 * 72];
    __shared__ ushort Ps[4 * 16 * 72];
    int tile = blockIdx.x;
    int hh = blockIdx.y;
    int segStart, q0, nkt;
    if (tile < 16) { segStart = 0; q0 = tile << 6; nkt = 16; }
    else { segStart = S0; q0 = S0 + ((tile - 16) << 6); nkt = 8; }
    const int t = threadIdx.x;
    const int wave = t >> 6, lane = t & 63;
    const int c = lane & 15, fq = lane >> 4;
    const int wq = wave << 4;
    ushort* Pw = Ps + wave * 16 * 72;

    bf16x8 qf[2];
    #pragma unroll
    for (int ks = 0; ks < 2; ++ks)
        qf[ks] = *(const bf16x8*)(qkb + (size_t)(q0 + wq + c) * QKS + hh * HD + ks * 32 + fq * 8);

    float m_i[4], l_i[4];
    f32x4 accO[4];
    #pragma unroll
    for (int r = 0; r < 4; ++r) { m_i[r] = -1e30f; l_i[r] = 0.f; }
    #pragma unroll
    for (int nt = 0; nt < 4; ++nt) accO[nt] = (f32x4){0.f, 0.f, 0.f, 0.f};

    for (int kt = 0; kt < nkt; ++kt) {
        int kbase = segStart + (kt << 6);
        __syncthreads();
        #pragma unroll
        for (int i = 0; i < 2; ++i) {
            int u = t + (i << 8);            // 512 ushort8 units
            int r = u >> 3, c8 = (u & 7) << 3;
            u16x8 kv = *(const u16x8*)(qkb + (size_t)(kbase + r) * QKS + 1024 + hh * HD + c8);
            *(u16x8*)(Ks + r * 72 + c8) = kv;
            u16x8 vv = *(const u16x8*)(vT + ((size_t)hh * HD + r) * S_TOT + kbase + c8);
            *(u16x8*)(Vt + r * 72 + c8) = vv;
        }
        __syncthreads();

        f32x4 acc[4];
        #pragma unroll
        for (int nt = 0; nt < 4; ++nt) acc[nt] = (f32x4){0.f, 0.f, 0.f, 0.f};
        #pragma unroll
        for (int ks = 0; ks < 2; ++ks) {
            #pragma unroll
            for (int nt = 0; nt < 4; ++nt) {
                bf16x8 bfr = *(const bf16x8*)(Ks + (nt * 16 + c) * 72 + ks * 32 + fq * 8);
                acc[nt] = __builtin_amdgcn_mfma_f32_16x16x32_bf16(qf[ks], bfr, acc[nt], 0, 0, 0);
            }
        }

        #pragma unroll
        for (int r = 0; r < 4; ++r) {
            float s0v = acc[0][r] * SCALEV, s1v = acc[1][r] * SCALEV;
            float s2v = acc[2][r] * SCALEV, s3v = acc[3][r] * SCALEV;
            float rm = fmaxf(fmaxf(s0v, s1v), fmaxf(s2v, s3v));
            #pragma unroll
            for (int msk = 1; msk < 16; msk <<= 1)
                rm = fmaxf(rm, __shfl_xor(rm, msk, 64));
            float mn = fmaxf(m_i[r], rm);
            float al = __expf(m_i[r] - mn);
            float p0 = __expf(s0v - mn), p1 = __expf(s1v - mn);
            float p2 = __expf(s2v - mn), p3 = __expf(s3v - mn);
            float rs = p0 + p1 + p2 + p3;
            #pragma unroll
            for (int msk = 1; msk < 16; msk <<= 1)
                rs += __shfl_xor(rs, msk, 64);
            l_i[r] = l_i[r] * al + rs;
            m_i[r] = mn;
            #pragma unroll
            for (int nt = 0; nt < 4; ++nt) accO[nt][r] *= al;
            int qrow = (fq << 2) + r;
            Pw[qrow * 72 + 0  + c] = f2bf(p0);
            Pw[qrow * 72 + 16 + c] = f2bf(p1);
            Pw[qrow * 72 + 32 + c] = f2bf(p2);
            Pw[qrow * 72 + 48 + c] = f2bf(p3);
        }

        #pragma unroll
        for (int ks = 0; ks < 2; ++ks) {
            bf16x8 pa = *(const bf16x8*)(Pw + c * 72 + ks * 32 + fq * 8);
            #pragma unroll
            for (int nt = 0; nt < 4; ++nt) {
                bf16x8 bv = *(const bf16x8*)(Vt + (nt * 16 + c) * 72 + ks * 32 + fq * 8);
                accO[nt] = __builtin_amdgcn_mfma_f32_16x16x32_bf16(pa, bv, accO[nt], 0, 0, 0);
            }
        }
    }

    #pragma unroll
    for (int r = 0; r < 4; ++r) {
        float inv = 1.f / l_i[r];
        int row = q0 + wq + (fq << 2) + r;
        #pragma unroll
        for (int nt = 0; nt < 4; ++nt)
            o[(size_t)row * HID + hh * HD + nt * 16 + c] = f2bf(accO[nt][r] * inv);
    }
}

// ---------------- copy to out ----------------
__global__ __launch_bounds__(256) void copy_kernel(
    const float* __restrict__ src, float* __restrict__ dst, int n)
{
    int i = blockIdx.x * 256 + threadIdx.x;
    if (i < n) dst[i] = src[i];
}

extern "C" void kernel_launch(void* const* d_in, const int* in_sizes, int n_in,
                              void* d_out, int out_size, void* d_ws, size_t ws_size,
                              hipStream_t stream)
{
    const float* img0        = (const float*)d_in[0];
    const float* img1        = (const float*)d_in[1];
    const float* conv_w      = (const float*)d_in[2];
    const float* ln_pre_w    = (const float*)d_in[3];
    const float* attn_norm_w = (const float*)d_in[4];
    const float* q_w         = (const float*)d_in[5];
    const float* k_w         = (const float*)d_in[6];
    const float* v_w         = (const float*)d_in[7];
    const float* o_w         = (const float*)d_in[8];
    const float* ffn_norm_w  = (const float*)d_in[9];
    const float* gate_w      = (const float*)d_in[10];
    const float* up_w        = (const float*)d_in[11];
    const float* down_w      = (const float*)d_in[12];

    char* p = (char*)d_ws;
    float* x    = (float*)p;   p += (size_t)1572864 * 4;   // [1536][1024]
    float* cs   = (float*)p;   p += (size_t)49152 * 4;
    float* sn   = (float*)p;   p += (size_t)49152 * 4;
    ushort* qkb = (ushort*)p;  p += (size_t)3145728 * 2;   // [1536][2048] rope'd q|k bf16
    ushort* vb  = (ushort*)p;  p += (size_t)1572864 * 2;   // [1536][1024] v bf16
    ushort* vTb = (ushort*)p;  p += (size_t)1572864 * 2;   // [16][64][1536] V^T bf16
    ushort* hnb = (ushort*)p;  p += (size_t)1572864 * 2;   // [1536][1024]
    ushort* obb = (ushort*)p;  p += (size_t)1572864 * 2;   // [1536][1024]
    ushort* gb  = (ushort*)p;  p += (size_t)6291456 * 2;   // [1536][4096] silu(g)*u bf16
    float* skP  = (float*)p;   p += (size_t)6291456 * 4;   // 4 x [1536][1024] f32 partials
    ushort* Pb  = (ushort*)p;  p += (size_t)1179648 * 2;   // [1536][768]
    ushort* cvb = (ushort*)p;  p += (size_t)786432 * 2;    // conv_w bf16
    ushort* wbuf= (ushort*)p;  p += (size_t)16777216 * 2;  // per-layer weights

    ushort* wqkv = wbuf;                 // [3072][1024]
    ushort* wo   = wbuf + 3145728;       // [1024][1024]
    ushort* wgu  = wbuf + 4194304;       // [8192][1024] gu-interleaved
    ushort* wdn  = wbuf + 12582912;      // [1024][4096]

    dim3 blk(256);

    cvt_kernel<<<768, blk, 0, stream>>>(conv_w, cvb, 786432 / 4);
    im2col_kernel<<<S_TOT, blk, 0, stream>>>(img0, img1, Pb);
    gemm2p<64, 64, false><<<dim3(24, 16), blk, 0, stream>>>(
        Pb, cvb, x, S_TOT, HID, KCONV);
    rms_kernel<<<S_TOT, blk, 0, stream>>>(x, ln_pre_w, x);
    rope_tab_kernel<<<S_TOT, 32, 0, stream>>>(cs, sn);

    for (int l = 0; l < NLAYERS; ++l) {
        cvt_layer_kernel<<<16384, blk, 0, stream>>>(
            q_w + (size_t)l * 1048576, k_w + (size_t)l * 1048576,
            v_w + (size_t)l * 1048576, o_w + (size_t)l * 1048576,
            gate_w + (size_t)l * 4194304, up_w + (size_t)l * 4194304,
            down_w + (size_t)l * 4194304, wbuf);

        rms_bf_kernel<<<S_TOT, blk, 0, stream>>>(x, attn_norm_w + (size_t)l * HID, hnb);
        // qkv GEMM with fused RoPE: writes qkb (rope'd q|k bf16) and vb (v bf16)
        gemm2p_qkv<<<dim3(12, 24), blk, 0, stream>>>(
            hnb, wqkv, qkb, vb, cs, sn, HID);
        vtrans_bf_kernel<<<dim3(24, HEADS), blk, 0, stream>>>(vb, vTb);
        flash_mfma_kernel<<<dim3(24, HEADS), blk, 0, stream>>>(qkb, vTb, obb);
        // o-projection: partials then x += sum (residual already in x)
        gemm2p_sk<4><<<dim3(12, 8, 4), blk, 0, stream>>>(
            obb, wo, skP, S_TOT, HID, HID);
        reduce4_kernel<<<1536, blk, 0, stream>>>(skP, x, S_TOT * HID / 4);
        rms_bf_kernel<<<S_TOT, blk, 0, stream>>>(x, ffn_norm_w + (size_t)l * HID, hnb);
        // gate/up GEMM with fused SiLU: writes gb bf16 directly
        gemm2p_gu<<<dim3(12, 64), blk, 0, stream>>>(hnb, wgu, gb, HID);
        // down-projection: split-K=4 partials + reduce
        gemm2p_sk<4><<<dim3(12, 8, 4), blk, 0, stream>>>(
            gb, wdn, skP, S_TOT, HID, INTER);
        reduce4_kernel<<<1536, blk, 0, stream>>>(skP, x, S_TOT * HID / 4);
    }
    copy_kernel<<<(S_TOT * HID) / 256, blk, 0, stream>>>(x, (float*)d_out, S_TOT * HID);
}